// Round 3
// baseline (10370.525 us; speedup 1.0000x reference)
//
#include <hip/hip_runtime.h>

typedef unsigned short u16;
typedef unsigned int   u32;

#define B_  64
#define L_  384
#define CS  512   // SRC_DIM
#define H_  512
#define E_  256
#define NC  250
#define T_  127

__device__ __forceinline__ float h2f(u16 u){ _Float16 h; __builtin_memcpy(&h,&u,2); return (float)h; }
__device__ __forceinline__ u16  f2h(float f){ _Float16 h=(_Float16)f; u16 u; __builtin_memcpy(&u,&h,2); return u; }
__device__ __forceinline__ float wredsum(float v){
#pragma unroll
  for (int o=32;o>0;o>>=1) v += __shfl_down(v, o, 64);
  return v;
}
__device__ __forceinline__ float tanh_f(float x){
  x = fminf(fmaxf(x, -15.f), 15.f);
  float e = __expf(2.f*x);
  return (e-1.f)/(e+1.f);
}
__device__ __forceinline__ float sigm_f(float x){
  x = fminf(fmaxf(x, -30.f), 30.f);
  return 1.f/(1.f+__expf(-x));
}
__device__ __forceinline__ float dot4(float4 a, float4 b){
  return a.x*b.x + a.y*b.y + a.z*b.z + a.w*b.w;
}

// ---------------- GEMM1: src_feat[m][n] = sum_k src[m][k]*Wi2h[n][k] (f32 in, f16 out)
// M=24576, N=512, K=512 -> tiles 128x128, TK=8, 256 threads, 8x8 micro. No guards (all divisible).
__global__ __launch_bounds__(256) void gemm_srcfeat(
    const float* __restrict__ A, const float* __restrict__ W, u16* __restrict__ Cd,
    int M, int N, int K)
{
  __shared__ float As[8][128+4];
  __shared__ float Ws[8][128+4];
  const int tid = threadIdx.x;
  const int bm = blockIdx.x * 128;
  const int bn = blockIdx.y * 128;
  const int lr = tid >> 1;          // 0..127
  const int lc = (tid & 1) * 4;     // 0 or 4
  const int ty = tid >> 4, tx = tid & 15;
  float acc[8][8];
#pragma unroll
  for (int i=0;i<8;i++)
#pragma unroll
    for (int j=0;j<8;j++) acc[i][j]=0.f;

  for (int k0=0;k0<K;k0+=8){
    float4 va = *(const float4*)(A + (size_t)(bm+lr)*K + k0 + lc);
    float4 vw = *(const float4*)(W + (size_t)(bn+lr)*K + k0 + lc);
    As[lc+0][lr]=va.x; As[lc+1][lr]=va.y; As[lc+2][lr]=va.z; As[lc+3][lr]=va.w;
    Ws[lc+0][lr]=vw.x; Ws[lc+1][lr]=vw.y; Ws[lc+2][lr]=vw.z; Ws[lc+3][lr]=vw.w;
    __syncthreads();
#pragma unroll
    for (int k=0;k<8;k++){
      float a[8], w[8];
#pragma unroll
      for (int i=0;i<8;i++) a[i]=As[k][ty*8+i];
#pragma unroll
      for (int j=0;j<8;j++) w[j]=Ws[k][tx*8+j];
#pragma unroll
      for (int i=0;i<8;i++)
#pragma unroll
        for (int j=0;j<8;j++) acc[i][j] += a[i]*w[j];
    }
    __syncthreads();
  }
#pragma unroll
  for (int i=0;i<8;i++){
    int m = bm + ty*8 + i;
    u16* cp = Cd + (size_t)m*N + bn + tx*8;
    ushort4 o0, o1;
    o0.x=f2h(acc[i][0]); o0.y=f2h(acc[i][1]); o0.z=f2h(acc[i][2]); o0.w=f2h(acc[i][3]);
    o1.x=f2h(acc[i][4]); o1.y=f2h(acc[i][5]); o1.z=f2h(acc[i][6]); o1.w=f2h(acc[i][7]);
    *(ushort4*)cp = o0;
    *(ushort4*)(cp+4) = o1;
  }
}

// ---------------- GEMM2: probs[m][n] = sum_k hs[m][k]*Wgen[n][k] + bgen[n] (A f16, W f32, out f32)
// M=8128 (127*64), N=250, K=512. Tile 64x64, TK=16, guards on N.
__global__ __launch_bounds__(256) void gemm_probs(
    const u16* __restrict__ A, const float* __restrict__ W, const float* __restrict__ bias,
    float* __restrict__ Cd, int M, int N, int K)
{
  __shared__ float As[16][64+1];
  __shared__ float Ws[16][64+1];
  const int tid = threadIdx.x;
  const int bm = blockIdx.x*64, bn = blockIdx.y*64;
  const int lr = tid>>2;        // 0..63
  const int lc = (tid&3)*4;     // 0,4,8,12
  const int ty = tid>>4, tx = tid&15;
  float acc[4][4];
#pragma unroll
  for (int i=0;i<4;i++)
#pragma unroll
    for (int j=0;j<4;j++) acc[i][j]=0.f;

  for (int k0=0;k0<K;k0+=16){
    ushort4 va = *(const ushort4*)(A + (size_t)(bm+lr)*K + k0 + lc);
    As[lc+0][lr]=h2f(va.x); As[lc+1][lr]=h2f(va.y); As[lc+2][lr]=h2f(va.z); As[lc+3][lr]=h2f(va.w);
    int n = bn + lr;
    if (n < N){
      float4 vw = *(const float4*)(W + (size_t)n*K + k0 + lc);
      Ws[lc+0][lr]=vw.x; Ws[lc+1][lr]=vw.y; Ws[lc+2][lr]=vw.z; Ws[lc+3][lr]=vw.w;
    } else {
      Ws[lc+0][lr]=0.f; Ws[lc+1][lr]=0.f; Ws[lc+2][lr]=0.f; Ws[lc+3][lr]=0.f;
    }
    __syncthreads();
#pragma unroll
    for (int k=0;k<16;k++){
      float a[4], w[4];
#pragma unroll
      for (int i=0;i<4;i++) a[i]=As[k][ty*4+i];
#pragma unroll
      for (int j=0;j<4;j++) w[j]=Ws[k][tx*4+j];
#pragma unroll
      for (int i=0;i<4;i++)
#pragma unroll
        for (int j=0;j<4;j++) acc[i][j] += a[i]*w[j];
    }
    __syncthreads();
  }
#pragma unroll
  for (int i=0;i<4;i++){
    int m = bm + ty*4 + i;
#pragma unroll
    for (int j=0;j<4;j++){
      int n = bn + tx*4 + j;
      if (n < N) Cd[(size_t)m*N + n] = acc[i][j] + bias[n];
    }
  }
}

// ---------------- proj[b][h] = dot(h_prev[b,:], Wh2h[h,:]) + bh2h[h]   (one wave per output)
__global__ __launch_bounds__(256) void k_proj(const float* __restrict__ h,
    const float* __restrict__ Wh2h, const float* __restrict__ bh2h, float* __restrict__ proj)
{
  int gw = blockIdx.x*4 + (threadIdx.x>>6);  // 0..32767
  int lane = threadIdx.x & 63;
  int b = gw >> 9, hh = gw & 511;
  const float* hp = h + (b<<9) + lane*8;
  const float* wp = Wh2h + ((size_t)hh<<9) + lane*8;
  float4 h0 = *(const float4*)hp;
  float4 h1 = *(const float4*)(hp+4);
  float4 w0 = *(const float4*)wp;
  float4 w1 = *(const float4*)(wp+4);
  float v = dot4(h0,w0) + dot4(h1,w1);
  v = wredsum(v);
  if (!lane) proj[(b<<9)+hh] = v + bh2h[hh];
}

// ---------------- logit[b*L+l] = dot(wscore, tanh(src_feat[b,l,:]+proj[b,:])) (one wave per (b,l))
__global__ __launch_bounds__(256) void k_logit(const u16* __restrict__ sf,
    const float* __restrict__ proj, const float* __restrict__ wsc, float* __restrict__ logit)
{
  int gw = blockIdx.x*4 + (threadIdx.x>>6);   // = b*L + l
  int lane = threadIdx.x & 63;
  int b = gw / L_;
  const u16*   sp = sf + ((size_t)gw<<9) + lane*8;
  const float* pp = proj + (b<<9) + lane*8;
  const float* wp = wsc + lane*8;
  ushort4 s0=*(const ushort4*)sp, s1=*(const ushort4*)(sp+4);
  float4 p0=*(const float4*)pp, p1=*(const float4*)(pp+4);
  float4 w0=*(const float4*)wp, w1=*(const float4*)(wp+4);
  float v = tanh_f(h2f(s0.x)+p0.x)*w0.x + tanh_f(h2f(s0.y)+p0.y)*w0.y
          + tanh_f(h2f(s0.z)+p0.z)*w0.z + tanh_f(h2f(s0.w)+p0.w)*w0.w
          + tanh_f(h2f(s1.x)+p1.x)*w1.x + tanh_f(h2f(s1.y)+p1.y)*w1.y
          + tanh_f(h2f(s1.z)+p1.z)*w1.z + tanh_f(h2f(s1.w)+p1.w)*w1.w;
  v = wredsum(v);
  if (!lane) logit[gw] = v;
}

// ---------------- softmax over L + context[b][c] = sum_l alpha[l]*src[b,l,c]
// grid: (b, c-chunk of 128) = 64*4 blocks, 128 threads
__global__ __launch_bounds__(128) void k_ctx(const float* __restrict__ logit,
    const float* __restrict__ src, float* __restrict__ ctx)
{
  __shared__ float al[L_];
  __shared__ float red[4];
  int b  = blockIdx.x >> 2;
  int cc = (blockIdx.x & 3) << 7;
  int tid = threadIdx.x;
  const float* lp = logit + b*L_;
  float v0=lp[tid], v1=lp[tid+128], v2=lp[tid+256];
  float m = fmaxf(fmaxf(v0,v1),v2);
#pragma unroll
  for (int o=32;o>0;o>>=1) m = fmaxf(m, __shfl_down(m,o,64));
  if ((tid&63)==0) red[tid>>6]=m;
  __syncthreads();
  m = fmaxf(red[0],red[1]);
  float e0=__expf(v0-m), e1=__expf(v1-m), e2=__expf(v2-m);
  al[tid]=e0; al[tid+128]=e1; al[tid+256]=e2;
  float s = e0+e1+e2;
#pragma unroll
  for (int o=32;o>0;o>>=1) s += __shfl_down(s,o,64);
  if ((tid&63)==0) red[2+(tid>>6)]=s;
  __syncthreads();
  float inv = 1.f/(red[2]+red[3]);
  int ccol = cc + tid;
  const float* sp = src + (((size_t)b*L_)<<9) + ccol;
  float acc = 0.f;
#pragma unroll 4
  for (int l=0;l<L_;l++) acc += al[l]*sp[(size_t)l<<9];
  ctx[(b<<9)+ccol] = acc*inv;
}

// ---------------- LSTM cell: gates + state update + hs store (one wave per (b,h))
__global__ __launch_bounds__(256) void k_cell(
    const float* __restrict__ ctx, const int* __restrict__ text,
    const float* __restrict__ embt,
    const float* __restrict__ W_ih, const float* __restrict__ b_ih,
    const float* __restrict__ W_hh, const float* __restrict__ b_hh,
    const float* __restrict__ hprev, float* __restrict__ c,
    float* __restrict__ hnew, u16* __restrict__ hs, int t)
{
  int gw = blockIdx.x*4 + (threadIdx.x>>6);   // 0..32767
  int lane = threadIdx.x & 63;
  int b = gw >> 9, hh = gw & 511;
  const float* cp = ctx + (b<<9) + lane*8;
  float4 x0=*(const float4*)cp, x1=*(const float4*)(cp+4);
  int tok = text[b*T_ + t];
  const float* ep = embt + (size_t)tok*E_ + lane*4;
  float4 ev = *(const float4*)ep;
  const float* hp = hprev + (b<<9) + lane*8;
  float4 hv0=*(const float4*)hp, hv1=*(const float4*)(hp+4);
  float g4[4];
#pragma unroll
  for (int g=0; g<4; g++){
    int j = (g<<9) + hh;
    const float* wi = W_ih + (size_t)j*768;
    float4 a0 = *(const float4*)(wi + lane*8);
    float4 a1 = *(const float4*)(wi + lane*8 + 4);
    float4 a2 = *(const float4*)(wi + 512 + lane*4);
    const float* wh = W_hh + ((size_t)j<<9) + lane*8;
    float4 b0 = *(const float4*)wh;
    float4 b1 = *(const float4*)(wh+4);
    float v = dot4(x0,a0) + dot4(x1,a1) + dot4(ev,a2) + dot4(hv0,b0) + dot4(hv1,b1);
    g4[g] = wredsum(v);
  }
  if (!lane){
    float gi = g4[0] + b_ih[hh]      + b_hh[hh];
    float gf = g4[1] + b_ih[512+hh]  + b_hh[512+hh];
    float gg = g4[2] + b_ih[1024+hh] + b_hh[1024+hh];
    float go = g4[3] + b_ih[1536+hh] + b_hh[1536+hh];
    float fi = sigm_f(gi), ff = sigm_f(gf), fg = tanh_f(gg), fo = sigm_f(go);
    float cn = ff*c[gw] + fi*fg;
    float hn = fo*tanh_f(cn);
    c[gw] = cn;
    hnew[gw] = hn;
    hs[(((size_t)(b*T_ + t))<<9) + hh] = f2h(hn);
  }
}

extern "C" void kernel_launch(void* const* d_in, const int* in_sizes, int n_in,
                              void* d_out, int out_size, void* d_ws, size_t ws_size,
                              hipStream_t stream)
{
  const float* src   = (const float*)d_in[0];
  const int*   text  = (const int*)d_in[1];
  const float* embt  = (const float*)d_in[2];
  const float* Wi2h  = (const float*)d_in[3];
  const float* Wh2h  = (const float*)d_in[4];
  const float* bh2h  = (const float*)d_in[5];
  const float* wsc   = (const float*)d_in[6];
  const float* W_ih  = (const float*)d_in[7];
  const float* b_ih  = (const float*)d_in[8];
  const float* W_hh  = (const float*)d_in[9];
  const float* b_hh  = (const float*)d_in[10];
  const float* Wgen  = (const float*)d_in[11];
  const float* bgen  = (const float*)d_in[12];
  float* out = (float*)d_out;

  // Workspace: sf/hs in f16 -> ~34 MB total.
  char* wsb   = (char*)d_ws;
  u16*  sf    = (u16*)wsb;                                  // B*L*H  f16 = 25.2 MB
  u16*  hs    = sf + (size_t)B_*L_*H_;                      // B*T*H  f16 =  8.3 MB
  float* h0   = (float*)(hs + (size_t)B_*T_*H_);            // B*H f32
  float* h1   = h0 + B_*H_;
  float* cbuf = h1 + B_*H_;
  float* proj = cbuf + B_*H_;
  float* logit= proj + B_*H_;                               // B*L f32
  float* ctx  = logit + B_*L_;                              // B*H f32

  hipMemsetAsync(h0,   0, (size_t)B_*H_*sizeof(float), stream);
  hipMemsetAsync(cbuf, 0, (size_t)B_*H_*sizeof(float), stream);

  dim3 g1(B_*L_/128, H_/128);
  gemm_srcfeat<<<g1, 256, 0, stream>>>(src, Wi2h, sf, B_*L_, H_, CS);

  float* hcur = h0;
  float* hnxt = h1;
  for (int t=0; t<T_; t++){
    k_proj <<<8192, 256, 0, stream>>>(hcur, Wh2h, bh2h, proj);
    k_logit<<<6144, 256, 0, stream>>>(sf, proj, wsc, logit);
    k_ctx  <<<256, 128, 0, stream>>>(logit, src, ctx);
    k_cell <<<8192, 256, 0, stream>>>(ctx, text, embt, W_ih, b_ih, W_hh, b_hh,
                                      hcur, cbuf, hnxt, hs, t);
    float* tmp = hcur; hcur = hnxt; hnxt = tmp;
  }

  dim3 g2(B_*T_/64, (NC+63)/64);
  gemm_probs<<<g2, 256, 0, stream>>>(hs, Wgen, bgen, out, B_*T_, NC, H_);
}

// Round 4
// 9977.622 us; speedup vs baseline: 1.0394x; 1.0394x over previous
//
#include <hip/hip_runtime.h>

typedef unsigned short u16;
typedef unsigned int   u32;
typedef _Float16 f16;
typedef f16   f16x8 __attribute__((ext_vector_type(8)));
typedef float f32x4 __attribute__((ext_vector_type(4)));

#define B_  64
#define L_  384
#define CS  512   // SRC_DIM
#define H_  512
#define E_  256
#define NC  250
#define T_  127

__device__ __forceinline__ float h2f(u16 u){ f16 h; __builtin_memcpy(&h,&u,2); return (float)h; }
__device__ __forceinline__ u16  f2h(float f){ f16 h=(f16)f; u16 u; __builtin_memcpy(&u,&h,2); return u; }
__device__ __forceinline__ float wredsum(float v){
#pragma unroll
  for (int o=32;o>0;o>>=1) v += __shfl_down(v, o, 64);
  return v;
}
__device__ __forceinline__ float tanh_f(float x){
  x = fminf(fmaxf(x, -15.f), 15.f);
  float e = __expf(2.f*x);
  return (e-1.f)/(e+1.f);
}
__device__ __forceinline__ float sigm_f(float x){
  x = fminf(fmaxf(x, -30.f), 30.f);
  return 1.f/(1.f+__expf(-x));
}

// ---------------- one-time converters ----------------
__global__ __launch_bounds__(256) void k_cvt(const float* __restrict__ in, f16* __restrict__ o, int n){
  int i = blockIdx.x*256 + threadIdx.x;
  if (i < n) o[i] = (f16)in[i];
}
// Wg[r][0:768] = W_ih[r], Wg[r][768:1280] = W_hh[r]   (rows r = 4*512 gate rows)
__global__ __launch_bounds__(256) void k_packwg(const float* __restrict__ Wih,
    const float* __restrict__ Whh, f16* __restrict__ Wg){
  int i = blockIdx.x*256 + threadIdx.x;   // over 2048*1280
  if (i < 2048*1280){
    int r = i / 1280, c = i - r*1280;
    float v = (c < 768) ? Wih[(size_t)r*768 + c] : Whh[(size_t)r*512 + (c-768)];
    Wg[i] = (f16)v;
  }
}
// X0 emb part for t=0 (h part is memset 0; ctx part written by k_ctx step 0)
__global__ __launch_bounds__(256) void k_initx(const int* __restrict__ text,
    const float* __restrict__ embt, f16* __restrict__ X0){
  int b = blockIdx.x, col = threadIdx.x;
  int tok = text[b*T_];
  X0[(size_t)b*1280 + 512 + col] = (f16)embt[(size_t)tok*E_ + col];
}

// ---------------- GEMM1: src_feat = src @ Wi2h^T (f32 in, f16 out), 128x128 tiles
__global__ __launch_bounds__(256) void gemm_srcfeat(
    const float* __restrict__ A, const float* __restrict__ W, u16* __restrict__ Cd,
    int M, int N, int K)
{
  __shared__ float As[8][128+4];
  __shared__ float Ws[8][128+4];
  const int tid = threadIdx.x;
  const int bm = blockIdx.x * 128;
  const int bn = blockIdx.y * 128;
  const int lr = tid >> 1;
  const int lc = (tid & 1) * 4;
  const int ty = tid >> 4, tx = tid & 15;
  float acc[8][8];
#pragma unroll
  for (int i=0;i<8;i++)
#pragma unroll
    for (int j=0;j<8;j++) acc[i][j]=0.f;

  for (int k0=0;k0<K;k0+=8){
    float4 va = *(const float4*)(A + (size_t)(bm+lr)*K + k0 + lc);
    float4 vw = *(const float4*)(W + (size_t)(bn+lr)*K + k0 + lc);
    As[lc+0][lr]=va.x; As[lc+1][lr]=va.y; As[lc+2][lr]=va.z; As[lc+3][lr]=va.w;
    Ws[lc+0][lr]=vw.x; Ws[lc+1][lr]=vw.y; Ws[lc+2][lr]=vw.z; Ws[lc+3][lr]=vw.w;
    __syncthreads();
#pragma unroll
    for (int k=0;k<8;k++){
      float a[8], w[8];
#pragma unroll
      for (int i=0;i<8;i++) a[i]=As[k][ty*8+i];
#pragma unroll
      for (int j=0;j<8;j++) w[j]=Ws[k][tx*8+j];
#pragma unroll
      for (int i=0;i<8;i++)
#pragma unroll
        for (int j=0;j<8;j++) acc[i][j] += a[i]*w[j];
    }
    __syncthreads();
  }
#pragma unroll
  for (int i=0;i<8;i++){
    int m = bm + ty*8 + i;
    u16* cp = Cd + (size_t)m*N + bn + tx*8;
    ushort4 o0, o1;
    o0.x=f2h(acc[i][0]); o0.y=f2h(acc[i][1]); o0.z=f2h(acc[i][2]); o0.w=f2h(acc[i][3]);
    o1.x=f2h(acc[i][4]); o1.y=f2h(acc[i][5]); o1.z=f2h(acc[i][6]); o1.w=f2h(acc[i][7]);
    *(ushort4*)cp = o0;
    *(ushort4*)(cp+4) = o1;
  }
}

// ---------------- GEMM2: probs = hs @ Wgen^T + bgen (A f16, W f32, out f32)
__global__ __launch_bounds__(256) void gemm_probs(
    const u16* __restrict__ A, const float* __restrict__ W, const float* __restrict__ bias,
    float* __restrict__ Cd, int M, int N, int K)
{
  __shared__ float As[16][64+1];
  __shared__ float Ws[16][64+1];
  const int tid = threadIdx.x;
  const int bm = blockIdx.x*64, bn = blockIdx.y*64;
  const int lr = tid>>2;
  const int lc = (tid&3)*4;
  const int ty = tid>>4, tx = tid&15;
  float acc[4][4];
#pragma unroll
  for (int i=0;i<4;i++)
#pragma unroll
    for (int j=0;j<4;j++) acc[i][j]=0.f;

  for (int k0=0;k0<K;k0+=16){
    ushort4 va = *(const ushort4*)(A + (size_t)(bm+lr)*K + k0 + lc);
    As[lc+0][lr]=h2f(va.x); As[lc+1][lr]=h2f(va.y); As[lc+2][lr]=h2f(va.z); As[lc+3][lr]=h2f(va.w);
    int n = bn + lr;
    if (n < N){
      float4 vw = *(const float4*)(W + (size_t)n*K + k0 + lc);
      Ws[lc+0][lr]=vw.x; Ws[lc+1][lr]=vw.y; Ws[lc+2][lr]=vw.z; Ws[lc+3][lr]=vw.w;
    } else {
      Ws[lc+0][lr]=0.f; Ws[lc+1][lr]=0.f; Ws[lc+2][lr]=0.f; Ws[lc+3][lr]=0.f;
    }
    __syncthreads();
#pragma unroll
    for (int k=0;k<16;k++){
      float a[4], w[4];
#pragma unroll
      for (int i=0;i<4;i++) a[i]=As[k][ty*4+i];
#pragma unroll
      for (int j=0;j<4;j++) w[j]=Ws[k][tx*4+j];
#pragma unroll
      for (int i=0;i<4;i++)
#pragma unroll
        for (int j=0;j<4;j++) acc[i][j] += a[i]*w[j];
    }
    __syncthreads();
  }
#pragma unroll
  for (int i=0;i<4;i++){
    int m = bm + ty*4 + i;
#pragma unroll
    for (int j=0;j<4;j++){
      int n = bn + tx*4 + j;
      if (n < N) Cd[(size_t)m*N + n] = acc[i][j] + bias[n];
    }
  }
}

// ---------------- proj = h @ Wh2h^T + bh2h via MFMA. 8 blocks x 4 waves.
// X: [64][1280] f16, h at cols 768..1280. Wh: [512][512] f16 (row = out neuron).
__global__ __launch_bounds__(256) void k_proj(
    const f16* __restrict__ X, const f16* __restrict__ Wh,
    const float* __restrict__ bh2h, float* __restrict__ proj)
{
  int w = threadIdx.x >> 6, lane = threadIdx.x & 63;
  int quad = lane >> 4, l16 = lane & 15;
  int nbase = blockIdx.x*64 + w*16;
  const f16* bp  = Wh + (size_t)(nbase + l16)*512 + quad*8;
  const f16* ap0 = X  + (size_t)l16*1280 + 768 + quad*8;
  f32x4 acc[4] = {};
  for (int k0=0; k0<512; k0+=32){
    f16x8 bfr = *(const f16x8*)(bp + k0);
#pragma unroll
    for (int f=0; f<4; f++){
      f16x8 afr = *(const f16x8*)(ap0 + (size_t)f*16*1280 + k0);
      acc[f] = __builtin_amdgcn_mfma_f32_16x16x32_f16(afr, bfr, acc[f], 0,0,0);
    }
  }
  int n = nbase + l16;
  float bias = bh2h[n];
#pragma unroll
  for (int f=0; f<4; f++)
#pragma unroll
    for (int r=0; r<4; r++){
      int b = f*16 + quad*4 + r;
      proj[(b<<9) + n] = acc[f][r] + bias;
    }
}

// ---------------- logit[b*L+l] = dot(wscore, tanh(sf + proj))  (one wave per (b,l))
__global__ __launch_bounds__(256) void k_logit(const u16* __restrict__ sf,
    const float* __restrict__ proj, const float* __restrict__ wsc, float* __restrict__ logit)
{
  int gw = blockIdx.x*4 + (threadIdx.x>>6);
  int lane = threadIdx.x & 63;
  int b = gw / L_;
  const u16*   sp = sf + ((size_t)gw<<9) + lane*8;
  const float* pp = proj + (b<<9) + lane*8;
  const float* wp = wsc + lane*8;
  ushort4 s0=*(const ushort4*)sp, s1=*(const ushort4*)(sp+4);
  float4 p0=*(const float4*)pp, p1=*(const float4*)(pp+4);
  float4 w0=*(const float4*)wp, w1=*(const float4*)(wp+4);
  float v = tanh_f(h2f(s0.x)+p0.x)*w0.x + tanh_f(h2f(s0.y)+p0.y)*w0.y
          + tanh_f(h2f(s0.z)+p0.z)*w0.z + tanh_f(h2f(s0.w)+p0.w)*w0.w
          + tanh_f(h2f(s1.x)+p1.x)*w1.x + tanh_f(h2f(s1.y)+p1.y)*w1.y
          + tanh_f(h2f(s1.z)+p1.z)*w1.z + tanh_f(h2f(s1.w)+p1.w)*w1.w;
  v = wredsum(v);
  if (!lane) logit[gw] = v;
}

// ---------------- softmax + context -> writes X_cur ctx part (f16)
__global__ __launch_bounds__(128) void k_ctx(const float* __restrict__ logit,
    const float* __restrict__ src, f16* __restrict__ Xc)
{
  __shared__ float al[L_];
  __shared__ float red[4];
  int b  = blockIdx.x >> 2;
  int cc = (blockIdx.x & 3) << 7;
  int tid = threadIdx.x;
  const float* lp = logit + b*L_;
  float v0=lp[tid], v1=lp[tid+128], v2=lp[tid+256];
  float m = fmaxf(fmaxf(v0,v1),v2);
#pragma unroll
  for (int o=32;o>0;o>>=1) m = fmaxf(m, __shfl_down(m,o,64));
  if ((tid&63)==0) red[tid>>6]=m;
  __syncthreads();
  m = fmaxf(red[0],red[1]);
  float e0=__expf(v0-m), e1=__expf(v1-m), e2=__expf(v2-m);
  al[tid]=e0; al[tid+128]=e1; al[tid+256]=e2;
  float s = e0+e1+e2;
#pragma unroll
  for (int o=32;o>0;o>>=1) s += __shfl_down(s,o,64);
  if ((tid&63)==0) red[2+(tid>>6)]=s;
  __syncthreads();
  float inv = 1.f/(red[2]+red[3]);
  int ccol = cc + tid;
  const float* sp = src + (((size_t)b*L_)<<9) + ccol;
  float acc = 0.f;
#pragma unroll 4
  for (int l=0;l<L_;l++) acc += al[l]*sp[(size_t)l<<9];
  Xc[(size_t)b*1280 + ccol] = (f16)(acc*inv);
}

// ---------------- gates GEMM (MFMA) + fused LSTM cell update.
// 32 blocks x 4 waves; wave w = gate w; block j covers h in [j*16, j*16+16).
// Reads X (cur), writes cbuf, X_next (h part + emb part for t+1), hs.
__global__ __launch_bounds__(256) void k_gates(
    const f16* __restrict__ X, const f16* __restrict__ Wg,
    const float* __restrict__ b_ih, const float* __restrict__ b_hh,
    float* __restrict__ cbuf, f16* __restrict__ Xn, u16* __restrict__ hs,
    const int* __restrict__ text, const float* __restrict__ embt, int t)
{
  __shared__ float gbuf[4][64][16];
  int w = threadIdx.x >> 6, lane = threadIdx.x & 63;
  int quad = lane >> 4, l16 = lane & 15;
  int j = blockIdx.x;
  int row = w*512 + j*16 + l16;
  const f16* bp  = Wg + (size_t)row*1280 + quad*8;
  const f16* ap0 = X  + (size_t)l16*1280 + quad*8;
  f32x4 acc[4] = {};
  for (int k0=0; k0<1280; k0+=32){
    f16x8 bfr = *(const f16x8*)(bp + k0);
#pragma unroll
    for (int f=0; f<4; f++){
      f16x8 afr = *(const f16x8*)(ap0 + (size_t)f*16*1280 + k0);
      acc[f] = __builtin_amdgcn_mfma_f32_16x16x32_f16(afr, bfr, acc[f], 0,0,0);
    }
  }
#pragma unroll
  for (int f=0; f<4; f++)
#pragma unroll
    for (int r=0; r<4; r++)
      gbuf[w][f*16 + quad*4 + r][l16] = acc[f][r];
  __syncthreads();
  int tid = threadIdx.x;
#pragma unroll
  for (int i=0; i<4; i++){
    int cidx = tid + i*256;            // 0..1023 = 64 b x 16 h
    int b = cidx >> 4, hl = cidx & 15;
    int hg = j*16 + hl;
    float gi = gbuf[0][b][hl] + b_ih[hg]        + b_hh[hg];
    float gf = gbuf[1][b][hl] + b_ih[512+hg]    + b_hh[512+hg];
    float gg = gbuf[2][b][hl] + b_ih[1024+hg]   + b_hh[1024+hg];
    float go = gbuf[3][b][hl] + b_ih[1536+hg]   + b_hh[1536+hg];
    float fi=sigm_f(gi), ff=sigm_f(gf), fg=tanh_f(gg), fo=sigm_f(go);
    size_t ci = ((size_t)b<<9) + hg;
    float cn = ff*cbuf[ci] + fi*fg;
    float hn = fo*tanh_f(cn);
    cbuf[ci] = cn;
    Xn[(size_t)b*1280 + 768 + hg] = (f16)hn;
    hs[(((size_t)(b*T_ + t))<<9) + hg] = f2h(hn);
  }
  // block 0 prepares next step's embedding slice of X
  if (j == 0 && (t+1) < T_){
#pragma unroll
    for (int i=0; i<64; i++){
      int e = tid + i*256;             // 0..16383 = 64 b x 256 cols
      int b = e >> 8, col = e & 255;
      int tok = text[b*T_ + t + 1];
      Xn[(size_t)b*1280 + 512 + col] = (f16)embt[(size_t)tok*E_ + col];
    }
  }
}

extern "C" void kernel_launch(void* const* d_in, const int* in_sizes, int n_in,
                              void* d_out, int out_size, void* d_ws, size_t ws_size,
                              hipStream_t stream)
{
  const float* src   = (const float*)d_in[0];
  const int*   text  = (const int*)d_in[1];
  const float* embt  = (const float*)d_in[2];
  const float* Wi2h  = (const float*)d_in[3];
  const float* Wh2h  = (const float*)d_in[4];
  const float* bh2h  = (const float*)d_in[5];
  const float* wsc   = (const float*)d_in[6];
  const float* W_ih  = (const float*)d_in[7];
  const float* b_ih  = (const float*)d_in[8];
  const float* W_hh  = (const float*)d_in[9];
  const float* b_hh  = (const float*)d_in[10];
  const float* Wgen  = (const float*)d_in[11];
  const float* bgen  = (const float*)d_in[12];
  float* out = (float*)d_out;

  // Workspace layout (~40 MB)
  char* p = (char*)d_ws;
  u16*  sf    = (u16*)p;              p += (size_t)B_*L_*H_*2;     // 25.2 MB f16
  u16*  hs    = (u16*)p;              p += (size_t)B_*T_*H_*2;     //  8.3 MB f16
  f16*  WhF   = (f16*)p;              p += (size_t)H_*H_*2;        //  0.5 MB
  f16*  WgF   = (f16*)p;              p += (size_t)2048*1280*2;    //  5.2 MB
  f16*  X0    = (f16*)p;              p += (size_t)B_*1280*2;      //  160 KB
  f16*  X1    = (f16*)p;              p += (size_t)B_*1280*2;
  float* proj = (float*)p;            p += (size_t)B_*H_*4;
  float* logit= (float*)p;            p += (size_t)B_*L_*4;
  float* cbuf = (float*)p;            p += (size_t)B_*H_*4;

  hipMemsetAsync(X0,   0, (size_t)B_*1280*2, stream);
  hipMemsetAsync(cbuf, 0, (size_t)B_*H_*4, stream);

  // one-time weight conversions
  k_cvt   <<<(H_*H_+255)/256, 256, 0, stream>>>(Wh2h, WhF, H_*H_);
  k_packwg<<<(2048*1280+255)/256, 256, 0, stream>>>(W_ih, W_hh, WgF);
  k_initx <<<B_, 256, 0, stream>>>(text, embt, X0);

  dim3 g1(B_*L_/128, H_/128);
  gemm_srcfeat<<<g1, 256, 0, stream>>>(src, Wi2h, sf, B_*L_, H_, CS);

  for (int t=0; t<T_; t++){
    f16* Xc = (t & 1) ? X1 : X0;
    f16* Xn = (t & 1) ? X0 : X1;
    k_proj <<<8,    256, 0, stream>>>(Xc, WhF, bh2h, proj);
    k_logit<<<6144, 256, 0, stream>>>(sf, proj, wsc, logit);
    k_ctx  <<<256,  128, 0, stream>>>(logit, src, Xc);
    k_gates<<<32,   256, 0, stream>>>(Xc, WgF, b_ih, b_hh, cbuf, Xn, hs, text, embt, t);
  }

  dim3 g2(B_*T_/64, (NC+63)/64);
  gemm_probs<<<g2, 256, 0, stream>>>(hs, Wgen, bgen, out, B_*T_, NC, H_);
}